// Round 2
// baseline (900.931 us; speedup 1.0000x reference)
//
#include <hip/hip_runtime.h>
#include <hip/hip_bf16.h>

// Problem constants (from reference): B=4, L=1024, H=1024, E=16, NH=16, D=64
#define MTOK   4096     // B*L rows of the big GEMMs
#define HID    1024     // H
#define NSUB   65536    // MTOK*NH sub-tokens
#define DDIM   64       // head_dim == expert dim
#define NEXP   16

// ---------------------------------------------------------------------------
// SGEMM: C[M,N] = A[M,K] @ W[K,N] + bias[N]   (fp32, vector ALU)
// 128x128 tile, 256 threads, 8x8 micro-tile split as {0..3, 64..67} in both
// dims so ds_read_b128 is <=2-way bank-aliased (free). Register-prefetch
// double buffering hides HBM latency under the 16-deep K inner loop.
// COMBINE: A := A + A2 elementwise during staging (fuses top-2 combine).
// ---------------------------------------------------------------------------
template <bool COMBINE>
__global__ __launch_bounds__(256) void sgemm128(
    const float* __restrict__ A, const float* __restrict__ A2,
    const float* __restrict__ Bw, const float* __restrict__ bias,
    float* __restrict__ C, int M, int N, int K)
{
    __shared__ float As[16][132];   // [k][m], stride 132 breaks write conflicts
    __shared__ float Bs[16][128];   // [k][n]

    const int tid = threadIdx.x;
    const int bm = blockIdx.y * 128;
    const int bn = blockIdx.x * 128;
    const int tx = tid & 15;        // col group
    const int ty = tid >> 4;        // row group

    // A-tile loader mapping: thread -> (row, k-quad); 128 rows x 16 k
    const int a_kq = (tid & 3) * 4;     // k offset (float4 along k)
    const int a_r  = tid >> 2;          // row 0..63 (+64 second pass)
    // B-tile loader mapping: 16 k x 128 n
    const int b_nq = (tid & 31) * 4;    // n offset (float4 along n)
    const int b_k  = tid >> 5;          // k 0..7 (+8 second pass)

    float acc[8][8];
#pragma unroll
    for (int i = 0; i < 8; i++)
#pragma unroll
        for (int j = 0; j < 8; j++) acc[i][j] = 0.f;

    float4 ra[2], ra2[2], rb[2];
    // prologue: load tile 0 into regs
#pragma unroll
    for (int rr = 0; rr < 2; rr++) {
        const int row = bm + a_r + rr * 64;
        ra[rr] = *(const float4*)&A[(size_t)row * K + a_kq];
        if (COMBINE) ra2[rr] = *(const float4*)&A2[(size_t)row * K + a_kq];
    }
#pragma unroll
    for (int kk = 0; kk < 2; kk++) {
        const int k = b_k + kk * 8;
        rb[kk] = *(const float4*)&Bw[(size_t)k * N + bn + b_nq];
    }

    const int ntiles = K / 16;
    for (int t = 0; t < ntiles; t++) {
        // stage regs -> LDS (A transposed to [k][m])
#pragma unroll
        for (int rr = 0; rr < 2; rr++) {
            float4 v = ra[rr];
            if (COMBINE) { v.x += ra2[rr].x; v.y += ra2[rr].y;
                           v.z += ra2[rr].z; v.w += ra2[rr].w; }
            const int row = a_r + rr * 64;
            As[a_kq + 0][row] = v.x; As[a_kq + 1][row] = v.y;
            As[a_kq + 2][row] = v.z; As[a_kq + 3][row] = v.w;
        }
#pragma unroll
        for (int kk = 0; kk < 2; kk++)
            *(float4*)&Bs[b_k + kk * 8][b_nq] = rb[kk];
        __syncthreads();

        // prefetch next tile (overlaps with compute below)
        if (t + 1 < ntiles) {
            const int k0 = (t + 1) * 16;
#pragma unroll
            for (int rr = 0; rr < 2; rr++) {
                const int row = bm + a_r + rr * 64;
                ra[rr] = *(const float4*)&A[(size_t)row * K + k0 + a_kq];
                if (COMBINE) ra2[rr] = *(const float4*)&A2[(size_t)row * K + k0 + a_kq];
            }
#pragma unroll
            for (int kk = 0; kk < 2; kk++) {
                const int k = b_k + kk * 8;
                rb[kk] = *(const float4*)&Bw[(size_t)(k0 + k) * N + bn + b_nq];
            }
        }

#pragma unroll
        for (int k = 0; k < 16; k++) {
            float a[8], b[8];
            *(float4*)&a[0] = *(const float4*)&As[k][ty * 4];
            *(float4*)&a[4] = *(const float4*)&As[k][ty * 4 + 64];
            *(float4*)&b[0] = *(const float4*)&Bs[k][tx * 4];
            *(float4*)&b[4] = *(const float4*)&Bs[k][tx * 4 + 64];
#pragma unroll
            for (int i = 0; i < 8; i++)
#pragma unroll
                for (int j = 0; j < 8; j++)
                    acc[i][j] = fmaf(a[i], b[j], acc[i][j]);
        }
        __syncthreads();
    }

    // epilogue: bias + coalesced float4 stores
#pragma unroll
    for (int i = 0; i < 8; i++) {
        const int row = bm + ty * 4 + (i & 3) + (i >> 2) * 64;
#pragma unroll
        for (int jg = 0; jg < 2; jg++) {
            const int col = bn + tx * 4 + jg * 64;
            float4 v;
            v.x = acc[i][jg * 4 + 0] + bias[col + 0];
            v.y = acc[i][jg * 4 + 1] + bias[col + 1];
            v.z = acc[i][jg * 4 + 2] + bias[col + 2];
            v.w = acc[i][jg * 4 + 3] + bias[col + 3];
            *(float4*)&C[(size_t)row * N + col] = v;
        }
    }
}

// ---------------------------------------------------------------------------
// Router: per sub-token, logits = h_row @ emb[64x16], softmax, top-2.
// One thread per sub-token; emb staged in LDS (broadcast reads are free).
// Top-k tie-break matches jax.lax.top_k (stable: lowest index wins ties)
// via strict-> comparisons. Weights are raw softmax probs (NOT renormalized).
// ---------------------------------------------------------------------------
__global__ __launch_bounds__(256) void router_kernel(
    const float* __restrict__ h, const float* __restrict__ emb,
    int* __restrict__ selp, float2* __restrict__ rw)
{
    __shared__ float es[DDIM][NEXP];
    const int tid = threadIdx.x;
    for (int i = tid; i < DDIM * NEXP; i += 256) ((float*)es)[i] = emb[i];
    __syncthreads();

    const int n = blockIdx.x * 256 + tid;
    const float* hr = h + (size_t)n * DDIM;

    float lg[NEXP];
#pragma unroll
    for (int e = 0; e < NEXP; e++) lg[e] = 0.f;
    for (int i = 0; i < DDIM; i += 4) {
        const float4 hv = *(const float4*)&hr[i];
#pragma unroll
        for (int e = 0; e < NEXP; e++) {
            lg[e] = fmaf(hv.x, es[i + 0][e], lg[e]);
            lg[e] = fmaf(hv.y, es[i + 1][e], lg[e]);
            lg[e] = fmaf(hv.z, es[i + 2][e], lg[e]);
            lg[e] = fmaf(hv.w, es[i + 3][e], lg[e]);
        }
    }
    // stable softmax
    float m = lg[0];
#pragma unroll
    for (int e = 1; e < NEXP; e++) m = fmaxf(m, lg[e]);
    float p[NEXP], den = 0.f;
#pragma unroll
    for (int e = 0; e < NEXP; e++) { p[e] = expf(lg[e] - m); den += p[e]; }
    // top-2 on probs, stable tie-break (strict >)
    int i1 = 0; float v1 = p[0];
#pragma unroll
    for (int e = 1; e < NEXP; e++) if (p[e] > v1) { v1 = p[e]; i1 = e; }
    int i2 = (i1 == 0) ? 1 : 0; float v2 = p[i2];
#pragma unroll
    for (int e = 0; e < NEXP; e++)
        if (e != i1 && e != ((i1 == 0) ? 1 : 0) && p[e] > v2) { v2 = p[e]; i2 = e; }

    selp[n] = i1 | (i2 << 8);
    rw[n] = make_float2(v1 / den, v2 / den);
}

// ---------------------------------------------------------------------------
// Sparse expert MLP. Grid = (expert, token-chunk). Block stages the expert's
// w1/w2/w3 (48 KB) in LDS, then each wave scans its tokens; matched tokens
// are computed with lane = output-dim, __shfl broadcasting the activation.
// Each (token, slot) is written by exactly one block -> no atomics:
// slot0 -> pa plane, slot1 -> pb plane. GEMM2 adds the planes while staging.
// ---------------------------------------------------------------------------
__global__ __launch_bounds__(256) void expert_kernel(
    const float* __restrict__ h, const int* __restrict__ selp,
    const float2* __restrict__ rw,
    const float* __restrict__ w1, const float* __restrict__ b1,
    const float* __restrict__ w2, const float* __restrict__ b2,
    const float* __restrict__ w3, const float* __restrict__ b3,
    float* __restrict__ pa, float* __restrict__ pb)
{
    const int e = blockIdx.x;
    const int chunk = blockIdx.y;
    __shared__ float w1s[DDIM][DDIM], w2s[DDIM][DDIM], w3s[DDIM][DDIM];
    __shared__ float b1s[DDIM], b2s[DDIM], b3s[DDIM];

    const int tid = threadIdx.x;
    {
        const float4* g1 = (const float4*)(w1 + (size_t)e * DDIM * DDIM);
        const float4* g2 = (const float4*)(w2 + (size_t)e * DDIM * DDIM);
        const float4* g3 = (const float4*)(w3 + (size_t)e * DDIM * DDIM);
        for (int i = tid; i < DDIM * DDIM / 4; i += 256) {
            ((float4*)w1s)[i] = g1[i];
            ((float4*)w2s)[i] = g2[i];
            ((float4*)w3s)[i] = g3[i];
        }
        if (tid < DDIM) {
            b1s[tid] = b1[e * DDIM + tid];
            b2s[tid] = b2[e * DDIM + tid];
            b3s[tid] = b3[e * DDIM + tid];
        }
    }
    __syncthreads();

    const int wave = tid >> 6, lane = tid & 63;
    const int tok0 = chunk * (NSUB / 64);   // 1024 tokens per chunk

    for (int t = tok0 + wave; t < tok0 + NSUB / 64; t += 4) {
        const int sp = selp[t];
        const int s0 = sp & 0xff, s1 = (sp >> 8) & 0xff;
        if (s0 != e && s1 != e) continue;           // wave-uniform branch
        const float2 wv = rw[t];
        const float wgt = (s0 == e) ? wv.x : wv.y;
        float* outp = (s0 == e) ? pa : pb;

        const float hv = h[(size_t)t * DDIM + lane];
        float a1 = b1s[lane];
#pragma unroll
        for (int i = 0; i < DDIM; i++)
            a1 = fmaf(__shfl(hv, i), w1s[i][lane], a1);
        a1 = fmaxf(a1, 0.f);
        float a2 = b2s[lane];
#pragma unroll
        for (int i = 0; i < DDIM; i++)
            a2 = fmaf(__shfl(a1, i), w2s[i][lane], a2);
        a2 = fmaxf(a2, 0.f);
        float a3 = b3s[lane];
#pragma unroll
        for (int i = 0; i < DDIM; i++)
            a3 = fmaf(__shfl(a2, i), w3s[i][lane], a3);

        outp[(size_t)t * DDIM + lane] = wgt * a3;
    }
}

// ---------------------------------------------------------------------------
extern "C" void kernel_launch(void* const* d_in, const int* in_sizes, int n_in,
                              void* d_out, int out_size, void* d_ws, size_t ws_size,
                              hipStream_t stream)
{
    const float* x    = (const float*)d_in[0];
    const float* Wmh  = (const float*)d_in[1];
    const float* bmh  = (const float*)d_in[2];
    const float* emb  = (const float*)d_in[3];
    const float* w1   = (const float*)d_in[4];
    const float* b1   = (const float*)d_in[5];
    const float* w2   = (const float*)d_in[6];
    const float* b2   = (const float*)d_in[7];
    const float* w3   = (const float*)d_in[8];
    const float* b3   = (const float*)d_in[9];
    const float* Wm   = (const float*)d_in[10];
    const float* bm   = (const float*)d_in[11];
    float* out = (float*)d_out;

    // workspace layout (bytes): h 16M | pa 16M | pb 16M | selp 256K | rw 512K
    char* ws = (char*)d_ws;
    float*  h    = (float*)(ws);
    float*  pa   = (float*)(ws + (size_t)16777216);
    float*  pb   = (float*)(ws + (size_t)33554432);
    int*    selp = (int*)  (ws + (size_t)50331648);
    float2* rwp  = (float2*)(ws + (size_t)50593792);

    // 1) h = x @ Wmh + bmh     [4096,1024]
    sgemm128<false><<<dim3(HID / 128, MTOK / 128), 256, 0, stream>>>(
        x, nullptr, Wmh, bmh, h, MTOK, HID, HID);

    // 2) router: softmax(h @ emb), top-2
    router_kernel<<<NSUB / 256, 256, 0, stream>>>(h, emb, selp, rwp);

    // 3) sparse expert MLP -> slot planes pa, pb
    expert_kernel<<<dim3(NEXP, 64), 256, 0, stream>>>(
        h, selp, rwp, w1, b1, w2, b2, w3, b3, pa, pb);

    // 4) out = (pa + pb) @ Wm + bm
    sgemm128<true><<<dim3(HID / 128, MTOK / 128), 256, 0, stream>>>(
        pa, pb, Wm, bm, out, MTOK, HID, HID);
}

// Round 7
// 404.186 us; speedup vs baseline: 2.2290x; 2.2290x over previous
//
#include <hip/hip_runtime.h>
#include <hip/hip_bf16.h>

// Problem constants: B=4, L=1024, H=1024, E=16, NH=16, D=64
#define MTOK   4096     // B*L rows of the big GEMMs
#define HID    1024     // H
#define NSUB   65536    // MTOK*NH sub-tokens
#define DDIM   64       // head_dim == expert dim
#define NEXP   16

#define CAP    NSUB     // per-expert list capacity — overflow impossible
#define T_TILE 64       // tokens per expert_gemm tile

// LDS row stride (shorts) for gemm2 tiles: 32 data + 8 pad = 80 B = 5*16 B.
// Keeps every ds_read_b128 16B-aligned while spreading the 16 rows a
// quarter-wave reads across all 32 banks (2 lanes/bank = free, m136).
#define KSTR   40

typedef float  f32x4  __attribute__((ext_vector_type(4)));
typedef short  s16x8  __attribute__((ext_vector_type(8)));

// fp32 -> bf16 bits, round-to-nearest-even (inputs finite)
static __device__ __forceinline__ unsigned short f2bf(float f) {
    union { float f; unsigned u; } c; c.f = f;
    return (unsigned short)((c.u + 0x7fffu + ((c.u >> 16) & 1u)) >> 16);
}

// ---------------------------------------------------------------------------
// SGEMM (fp32 vector) — used for GEMM1 only (router numerics need ~fp32 h).
// ---------------------------------------------------------------------------
template <bool COMBINE>
__global__ __launch_bounds__(256) void sgemm128(
    const float* __restrict__ A, const float* __restrict__ A2,
    const float* __restrict__ Bw, const float* __restrict__ bias,
    float* __restrict__ C, int M, int N, int K)
{
    __shared__ float As[16][132];
    __shared__ float Bs[16][128];

    const int tid = threadIdx.x;
    const int bm = blockIdx.y * 128;
    const int bn = blockIdx.x * 128;
    const int tx = tid & 15;
    const int ty = tid >> 4;

    const int a_kq = (tid & 3) * 4;
    const int a_r  = tid >> 2;
    const int b_nq = (tid & 31) * 4;
    const int b_k  = tid >> 5;

    float acc[8][8];
#pragma unroll
    for (int i = 0; i < 8; i++)
#pragma unroll
        for (int j = 0; j < 8; j++) acc[i][j] = 0.f;

    float4 ra[2], ra2[2], rb[2];
#pragma unroll
    for (int rr = 0; rr < 2; rr++) {
        const int row = bm + a_r + rr * 64;
        ra[rr] = *(const float4*)&A[(size_t)row * K + a_kq];
        if (COMBINE) ra2[rr] = *(const float4*)&A2[(size_t)row * K + a_kq];
    }
#pragma unroll
    for (int kk = 0; kk < 2; kk++) {
        const int k = b_k + kk * 8;
        rb[kk] = *(const float4*)&Bw[(size_t)k * N + bn + b_nq];
    }

    const int ntiles = K / 16;
    for (int t = 0; t < ntiles; t++) {
#pragma unroll
        for (int rr = 0; rr < 2; rr++) {
            float4 v = ra[rr];
            if (COMBINE) { v.x += ra2[rr].x; v.y += ra2[rr].y;
                           v.z += ra2[rr].z; v.w += ra2[rr].w; }
            const int row = a_r + rr * 64;
            As[a_kq + 0][row] = v.x; As[a_kq + 1][row] = v.y;
            As[a_kq + 2][row] = v.z; As[a_kq + 3][row] = v.w;
        }
#pragma unroll
        for (int kk = 0; kk < 2; kk++)
            *(float4*)&Bs[b_k + kk * 8][b_nq] = rb[kk];
        __syncthreads();

        if (t + 1 < ntiles) {
            const int k0 = (t + 1) * 16;
#pragma unroll
            for (int rr = 0; rr < 2; rr++) {
                const int row = bm + a_r + rr * 64;
                ra[rr] = *(const float4*)&A[(size_t)row * K + k0 + a_kq];
                if (COMBINE) ra2[rr] = *(const float4*)&A2[(size_t)row * K + k0 + a_kq];
            }
#pragma unroll
            for (int kk = 0; kk < 2; kk++) {
                const int k = b_k + kk * 8;
                rb[kk] = *(const float4*)&Bw[(size_t)(k0 + k) * N + bn + b_nq];
            }
        }

#pragma unroll
        for (int k = 0; k < 16; k++) {
            float a[8], b[8];
            *(float4*)&a[0] = *(const float4*)&As[k][ty * 4];
            *(float4*)&a[4] = *(const float4*)&As[k][ty * 4 + 64];
            *(float4*)&b[0] = *(const float4*)&Bs[k][tx * 4];
            *(float4*)&b[4] = *(const float4*)&Bs[k][tx * 4 + 64];
#pragma unroll
            for (int i = 0; i < 8; i++)
#pragma unroll
                for (int j = 0; j < 8; j++)
                    acc[i][j] = fmaf(a[i], b[j], acc[i][j]);
        }
        __syncthreads();
    }

#pragma unroll
    for (int i = 0; i < 8; i++) {
        const int row = bm + ty * 4 + (i & 3) + (i >> 2) * 64;
#pragma unroll
        for (int jg = 0; jg < 2; jg++) {
            const int col = bn + tx * 4 + jg * 64;
            float4 v;
            v.x = acc[i][jg * 4 + 0] + bias[col + 0];
            v.y = acc[i][jg * 4 + 1] + bias[col + 1];
            v.z = acc[i][jg * 4 + 2] + bias[col + 2];
            v.w = acc[i][jg * 4 + 3] + bias[col + 3];
            *(float4*)&C[(size_t)row * N + col] = v;
        }
    }
}

// ---------------------------------------------------------------------------
__global__ void zero_cnt(int* __restrict__ cnt) { cnt[threadIdx.x] = 0; }

// ---------------------------------------------------------------------------
// Router: logits = h_row @ emb, softmax, top-2 (raw probs, stable tie-break
// matching jax.lax.top_k), then LDS-aggregated append of (token|slot<<16) to
// each selected expert's compact list (16 global atomics per block).
// ---------------------------------------------------------------------------
__global__ __launch_bounds__(256) void router_kernel(
    const float* __restrict__ h, const float* __restrict__ emb,
    float2* __restrict__ rw, int* __restrict__ cnt, int* __restrict__ lists)
{
    __shared__ float es[DDIM][NEXP];
    __shared__ int lcnt[NEXP], gbase[NEXP];
    const int tid = threadIdx.x;
    for (int i = tid; i < DDIM * NEXP; i += 256) ((float*)es)[i] = emb[i];
    if (tid < NEXP) lcnt[tid] = 0;
    __syncthreads();

    const int n = blockIdx.x * 256 + tid;
    const float* hr = h + (size_t)n * DDIM;

    float lg[NEXP];
#pragma unroll
    for (int e = 0; e < NEXP; e++) lg[e] = 0.f;
    for (int i = 0; i < DDIM; i += 4) {
        const float4 hv = *(const float4*)&hr[i];
#pragma unroll
        for (int e = 0; e < NEXP; e++) {
            lg[e] = fmaf(hv.x, es[i + 0][e], lg[e]);
            lg[e] = fmaf(hv.y, es[i + 1][e], lg[e]);
            lg[e] = fmaf(hv.z, es[i + 2][e], lg[e]);
            lg[e] = fmaf(hv.w, es[i + 3][e], lg[e]);
        }
    }
    float m = lg[0];
#pragma unroll
    for (int e = 1; e < NEXP; e++) m = fmaxf(m, lg[e]);
    float p[NEXP], den = 0.f;
#pragma unroll
    for (int e = 0; e < NEXP; e++) { p[e] = expf(lg[e] - m); den += p[e]; }
    int i1 = 0; float v1 = p[0];
#pragma unroll
    for (int e = 1; e < NEXP; e++) if (p[e] > v1) { v1 = p[e]; i1 = e; }
    int i2 = (i1 == 0) ? 1 : 0; float v2 = p[i2];
#pragma unroll
    for (int e = 0; e < NEXP; e++)
        if (e != i1 && e != ((i1 == 0) ? 1 : 0) && p[e] > v2) { v2 = p[e]; i2 = e; }

    const float invd = 1.f / den;
    rw[n] = make_float2(v1 * invd, v2 * invd);

    // LDS-aggregated compaction (i1 != i2 guarantees distinct slots)
    const int lp1 = atomicAdd(&lcnt[i1], 1);
    const int lp2 = atomicAdd(&lcnt[i2], 1);
    __syncthreads();
    if (tid < NEXP) gbase[tid] = atomicAdd(&cnt[tid], lcnt[tid]);
    __syncthreads();
    lists[i1 * CAP + gbase[i1] + lp1] = n;              // slot 0
    lists[i2 * CAP + gbase[i2] + lp2] = n | 0x10000;    // slot 1
}

// ---------------------------------------------------------------------------
// Expert GEMM over compacted lists. Block = (expert, 64-token tile).
// Weights in registers (lane owns out-dims jA, jA+32), activations ping-pong
// in LDS; wave-private token rows -> no barriers after initial staging.
// act reads are 32-lane broadcasts (free); weight loads are coalesced and
// amortized over 16 tokens/layer.
// ---------------------------------------------------------------------------
__global__ __launch_bounds__(256) void expert_gemm(
    const float* __restrict__ h, const int* __restrict__ cnt,
    const int* __restrict__ lists, const float2* __restrict__ rw,
    const float* __restrict__ w1, const float* __restrict__ b1,
    const float* __restrict__ w2, const float* __restrict__ b2,
    const float* __restrict__ w3, const float* __restrict__ b3,
    float* __restrict__ pa, float* __restrict__ pb)
{
    const int e    = blockIdx.x;
    const int base = blockIdx.y * T_TILE;
    const int ne   = cnt[e];
    if (base >= ne) return;
    const int nt = min(T_TILE, ne - base);

    __shared__ float act0[T_TILE][DDIM];
    __shared__ float act1[T_TILE][DDIM];
    __shared__ int   toks[T_TILE];

    const int tid  = threadIdx.x;
    const int wave = tid >> 6;
    const int lane = tid & 63;
    const int jA   = lane & 31;
    const int half = lane >> 5;

    if (tid < T_TILE) toks[tid] = (tid < nt) ? lists[e * CAP + base + tid] : 0;
    __syncthreads();

#pragma unroll
    for (int p = 0; p < T_TILE / 16; p++) {
        const int r = p * 16 + (tid >> 4);
        const int c = (tid & 15) * 4;
        if (r < nt) {
            const int t = toks[r] & 0xffff;
            *(float4*)&act0[r][c] = *(const float4*)&h[(size_t)t * DDIM + c];
        }
    }
    __syncthreads();

    float wa[DDIM], wb[DDIM];

#define LOAD_W(WP, BP, BA, BB) do {                                          \
        const float* wp_ = (WP) + (size_t)e * DDIM * DDIM;                   \
        _Pragma("unroll")                                                    \
        for (int i = 0; i < DDIM; i++) {                                     \
            wa[i] = wp_[i * DDIM + jA];                                      \
            wb[i] = wp_[i * DDIM + jA + 32];                                 \
        }                                                                    \
        BA = (BP)[e * DDIM + jA]; BB = (BP)[e * DDIM + jA + 32];             \
    } while (0)

#define DOT2(SRC, TR, AA, BB2) do {                                          \
        float a0 = 0.f, a1s = 0.f, b0 = 0.f, b1s = 0.f;                      \
        _Pragma("unroll")                                                    \
        for (int i = 0; i < 32; i += 4) {                                    \
            const float4 v = *(const float4*)&SRC[TR][i];                    \
            a0 = fmaf(v.x, wa[i + 0], a0); b0 = fmaf(v.x, wb[i + 0], b0);    \
            a0 = fmaf(v.y, wa[i + 1], a0); b0 = fmaf(v.y, wb[i + 1], b0);    \
            a0 = fmaf(v.z, wa[i + 2], a0); b0 = fmaf(v.z, wb[i + 2], b0);    \
            a0 = fmaf(v.w, wa[i + 3], a0); b0 = fmaf(v.w, wb[i + 3], b0);    \
        }                                                                    \
        _Pragma("unroll")                                                    \
        for (int i = 32; i < 64; i += 4) {                                   \
            const float4 v = *(const float4*)&SRC[TR][i];                    \
            a1s = fmaf(v.x, wa[i + 0], a1s); b1s = fmaf(v.x, wb[i + 0], b1s);\
            a1s = fmaf(v.y, wa[i + 1], a1s); b1s = fmaf(v.y, wb[i + 1], b1s);\
            a1s = fmaf(v.z, wa[i + 2], a1s); b1s = fmaf(v.z, wb[i + 2], b1s);\
            a1s = fmaf(v.w, wa[i + 3], a1s); b1s = fmaf(v.w, wb[i + 3], b1s);\
        }                                                                    \
        AA = a0 + a1s; BB2 = b0 + b1s;                                       \
    } while (0)

    float ba, bb;
    LOAD_W(w1, b1, ba, bb);
#pragma unroll
    for (int p = 0; p < T_TILE / 8; p++) {
        const int tr = p * 8 + wave * 2 + half;
        float aA, aB;
        DOT2(act0, tr, aA, aB);
        act1[tr][jA]      = fmaxf(aA + ba, 0.f);
        act1[tr][jA + 32] = fmaxf(aB + bb, 0.f);
    }
    LOAD_W(w2, b2, ba, bb);
#pragma unroll
    for (int p = 0; p < T_TILE / 8; p++) {
        const int tr = p * 8 + wave * 2 + half;
        float aA, aB;
        DOT2(act1, tr, aA, aB);
        act0[tr][jA]      = fmaxf(aA + ba, 0.f);
        act0[tr][jA + 32] = fmaxf(aB + bb, 0.f);
    }
    LOAD_W(w3, b3, ba, bb);
#pragma unroll
    for (int p = 0; p < T_TILE / 8; p++) {
        const int tr = p * 8 + wave * 2 + half;
        float aA, aB;
        DOT2(act0, tr, aA, aB);
        if (tr < nt) {
            const int en = toks[tr];
            const int t  = en & 0xffff;
            const float2 wv = rw[t];
            const float wgt = (en & 0x10000) ? wv.y : wv.x;
            float* dst = (en & 0x10000) ? pb : pa;
            dst[(size_t)t * DDIM + jA]      = (aA + ba) * wgt;
            dst[(size_t)t * DDIM + jA + 32] = (aB + bb) * wgt;
        }
    }
#undef LOAD_W
#undef DOT2
}

// ---------------------------------------------------------------------------
// Transpose + bf16-convert: WT[n][k] = bf16(W[k][n]).  64x64 tiles.
// ---------------------------------------------------------------------------
__global__ __launch_bounds__(256) void transpose_bf16(
    const float* __restrict__ W, unsigned short* __restrict__ WT, int K, int N)
{
    __shared__ float tile[64][65];
    const int k0 = blockIdx.x * 64;
    const int n0 = blockIdx.y * 64;
    const int tid = threadIdx.x;
    const int tr = tid >> 4;
    const int tc = (tid & 15) * 4;
#pragma unroll
    for (int p = 0; p < 4; p++) {
        const int r = p * 16 + tr;
        const float4 v = *(const float4*)&W[(size_t)(k0 + r) * N + n0 + tc];
        tile[r][tc + 0] = v.x; tile[r][tc + 1] = v.y;
        tile[r][tc + 2] = v.z; tile[r][tc + 3] = v.w;
    }
    __syncthreads();
#pragma unroll
    for (int p = 0; p < 4; p++) {
        const int n = p * 16 + tr;
        ushort4 o;
        o.x = f2bf(tile[tc + 0][n]); o.y = f2bf(tile[tc + 1][n]);
        o.z = f2bf(tile[tc + 2][n]); o.w = f2bf(tile[tc + 3][n]);
        *(ushort4*)&WT[(size_t)(n0 + n) * K + k0 + tc] = o;
    }
}

// ---------------------------------------------------------------------------
// GEMM2 via bf16 MFMA: C[M,N] = (pa+pb)[M,K] @ W[K,N] + bias, W given as
// WT[n][k] bf16. 128x128 tile, 4 waves each 64x64 (4x4 frags of 16x16x32).
// Fragment mapping (m89-verified family): A lane l holds A[l&15][(l>>4)*8+j];
// B lane l holds B[(l>>4)*8+j][l&15]; D col=l&15, row=(l>>4)*4+reg.
// LDS tiles are [row][k] with KSTR=40-short (80 B) stride: every b128 access
// stays 16B-aligned and a quarter-wave's 16 row-reads spread 2 lanes/bank
// (free, m136) instead of the 8-way conflict a 64 B stride would give.
// ---------------------------------------------------------------------------
__global__ __launch_bounds__(256) void gemm2_mfma(
    const float* __restrict__ pa, const float* __restrict__ pb,
    const unsigned short* __restrict__ WT, const float* __restrict__ bias,
    float* __restrict__ C, int M, int N, int K)
{
    __shared__ unsigned short A_bf[128][KSTR];   // [m][k] (+pad)
    __shared__ unsigned short B_bf[128][KSTR];   // [n][k] (+pad)

    const int tid  = threadIdx.x;
    const int bm   = blockIdx.y * 128;
    const int bn   = blockIdx.x * 128;
    const int wave = tid >> 6;
    const int lane = tid & 63;
    const int wm   = (wave >> 1) * 64;      // wave row offset in tile
    const int wn   = (wave & 1) * 64;       // wave col offset in tile
    const int r16  = lane & 15;
    const int g8   = (lane >> 4) * 8;

    const int srow = tid >> 1;              // staging row 0..127
    const int skh  = (tid & 1) * 16;        // staging k-half 0/16

    f32x4 acc[4][4];
#pragma unroll
    for (int i = 0; i < 4; i++)
#pragma unroll
        for (int j = 0; j < 4; j++) acc[i][j] = (f32x4){0.f, 0.f, 0.f, 0.f};

    for (int k0 = 0; k0 < K; k0 += 32) {
        // stage A: (pa+pb) row -> bf16
        {
            const float* pA = pa + (size_t)(bm + srow) * K + k0 + skh;
            const float* pB = pb + (size_t)(bm + srow) * K + k0 + skh;
            unsigned short tmp[16];
#pragma unroll
            for (int q = 0; q < 4; q++) {
                const float4 va = *(const float4*)&pA[q * 4];
                const float4 vb = *(const float4*)&pB[q * 4];
                tmp[q * 4 + 0] = f2bf(va.x + vb.x);
                tmp[q * 4 + 1] = f2bf(va.y + vb.y);
                tmp[q * 4 + 2] = f2bf(va.z + vb.z);
                tmp[q * 4 + 3] = f2bf(va.w + vb.w);
            }
            *(s16x8*)&A_bf[srow][skh]     = *(s16x8*)&tmp[0];
            *(s16x8*)&A_bf[srow][skh + 8] = *(s16x8*)&tmp[8];
        }
        // stage B: WT row (already bf16)
        {
            const unsigned short* pW = WT + (size_t)(bn + srow) * K + k0 + skh;
            *(s16x8*)&B_bf[srow][skh]     = *(const s16x8*)&pW[0];
            *(s16x8*)&B_bf[srow][skh + 8] = *(const s16x8*)&pW[8];
        }
        __syncthreads();

        s16x8 av[4], bv[4];
#pragma unroll
        for (int i = 0; i < 4; i++)
            av[i] = *(s16x8*)&A_bf[wm + i * 16 + r16][g8];
#pragma unroll
        for (int j = 0; j < 4; j++)
            bv[j] = *(s16x8*)&B_bf[wn + j * 16 + r16][g8];
#pragma unroll
        for (int i = 0; i < 4; i++)
#pragma unroll
            for (int j = 0; j < 4; j++)
                acc[i][j] = __builtin_amdgcn_mfma_f32_16x16x32_bf16(
                    av[i], bv[j], acc[i][j], 0, 0, 0);
        __syncthreads();
    }

    // epilogue: D col=l&15, row=(l>>4)*4+reg
#pragma unroll
    for (int i = 0; i < 4; i++)
#pragma unroll
        for (int j = 0; j < 4; j++) {
            const int col = bn + wn + j * 16 + r16;
            const float bv2 = bias[col];
#pragma unroll
            for (int r = 0; r < 4; r++) {
                const int row = bm + wm + i * 16 + (lane >> 4) * 4 + r;
                C[(size_t)row * N + col] = acc[i][j][r] + bv2;
            }
        }
}

// ---------------------------------------------------------------------------
extern "C" void kernel_launch(void* const* d_in, const int* in_sizes, int n_in,
                              void* d_out, int out_size, void* d_ws, size_t ws_size,
                              hipStream_t stream)
{
    const float* x    = (const float*)d_in[0];
    const float* Wmh  = (const float*)d_in[1];
    const float* bmh  = (const float*)d_in[2];
    const float* emb  = (const float*)d_in[3];
    const float* w1   = (const float*)d_in[4];
    const float* b1   = (const float*)d_in[5];
    const float* w2   = (const float*)d_in[6];
    const float* b2   = (const float*)d_in[7];
    const float* w3   = (const float*)d_in[8];
    const float* b3   = (const float*)d_in[9];
    const float* Wm   = (const float*)d_in[10];
    const float* bm   = (const float*)d_in[11];
    float* out = (float*)d_out;

    // ws: h 16M | pa 16M | pb 16M | rw 512K | cnt. WmT (2MB bf16) aliases h
    // (h is dead after expert_gemm; transpose launches after it).
    // lists (16*65536*4B = 4MB) lives in d_out (dead until gemm2 overwrites).
    char* ws = (char*)d_ws;
    float*  h     = (float*)(ws);
    float*  pa    = (float*)(ws + (size_t)(16 << 20));
    float*  pb    = (float*)(ws + (size_t)(32 << 20));
    float2* rwp   = (float2*)(ws + (size_t)(48 << 20));
    int*    cntp  = (int*)  (ws + (size_t)(48 << 20) + (NSUB * 8));
    unsigned short* WmT = (unsigned short*)(ws);
    int*    lists = (int*)  d_out;

    // 1) h = x @ Wmh + bmh   (fp32: router selection needs accurate h)
    sgemm128<false><<<dim3(HID / 128, MTOK / 128), 256, 0, stream>>>(
        x, nullptr, Wmh, bmh, h, MTOK, HID, HID);

    // 2) route + compact
    zero_cnt<<<1, NEXP, 0, stream>>>(cntp);
    router_kernel<<<NSUB / 256, 256, 0, stream>>>(h, emb, rwp, cntp, lists);

    // 3) sparse expert MLP -> slot planes pa, pb (h consumed here)
    expert_gemm<<<dim3(NEXP, CAP / T_TILE), 256, 0, stream>>>(
        h, cntp, lists, rwp, w1, b1, w2, b2, w3, b3, pa, pb);

    // 4) WmT[n][k] = bf16(Wm[k][n])   (clobbers h — now dead)
    transpose_bf16<<<dim3(HID / 64, HID / 64), 256, 0, stream>>>(
        Wm, WmT, HID, HID);

    // 5) out = (pa + pb) @ Wm + bm   (bf16 MFMA; routing already fixed)
    gemm2_mfma<<<dim3(HID / 128, MTOK / 128), 256, 0, stream>>>(
        pa, pb, WmT, bm, out, MTOK, HID, HID);
}